// Round 1
// baseline (170.490 us; speedup 1.0000x reference)
//
#include <hip/hip_runtime.h>
#include <stdint.h>

#define N_ROWS 4096
#define Z_DIM  2048
#define TOT    8192           // 2N rows of reps
#define RBYTES (Z_DIM / 2)    // 1024 B per fp4 row
#define BKE    128            // K elements per staging step
#define KBYT   (BKE / 2)      // 64 B per row per step
#define NITER  (Z_DIM / BKE)  // 16
#define BM     256            // tile rows
#define BN     128            // tile cols
#define NBLK   1056           // sum_{ri=0}^{31} (64 - 2*ri)
#define ABYTES (BM * KBYT)    // 16384 B of A per step
#define BUFB   (ABYTES + BN * KBYT)  // 24576 B per LDS buffer
#define INV_T  2.0f           // 1/temperature
#define SCL4   64.0f          // fp4 pre-scale; logits = acc * INV_T / SCL4^2

typedef __attribute__((ext_vector_type(4))) int   intx4;
typedef __attribute__((ext_vector_type(8))) int   intx8;
typedef __attribute__((ext_vector_type(4))) float floatx4;

#define GLOAD16(g, l)                                                   \
    __builtin_amdgcn_global_load_lds(                                   \
        (const __attribute__((address_space(1))) unsigned int*)(g),     \
        (__attribute__((address_space(3))) unsigned int*)(l), 16, 0, 0)

// branchless f32 -> fp4 e2m1 code (round to nearest level)
__device__ __forceinline__ unsigned int f2fp4(float v) {
    float a = fabsf(v);
    unsigned int c = (a >= 0.25f) + (a >= 0.75f) + (a >= 1.25f) + (a >= 1.75f)
                   + (a >= 2.5f)  + (a >= 3.5f)  + (a >= 5.0f);
    return c | (v < 0.f ? 8u : 0u);
}

// ---------------- kernel 1: row-normalize to fp4(e2m1, x64), pos, zero rowsum
__global__ __launch_bounds__(256) void normalize_kernel(
    const float* __restrict__ z1, const float* __restrict__ z2,
    unsigned char* __restrict__ reps, float* __restrict__ pos,
    float* __restrict__ rowsum)
{
    const int row  = blockIdx.x;          // 0..4095
    const int tid  = threadIdx.x;         // 0..255, 8 floats each
    const int lane = tid & 63, wave = tid >> 6;

    if (row < TOT / 256) rowsum[row * 256 + tid] = 0.f;   // fold in memset

    const float4* p1 = (const float4*)(z1 + (size_t)row * Z_DIM);
    const float4* p2 = (const float4*)(z2 + (size_t)row * Z_DIM);
    float4 x0 = p1[tid * 2], x1 = p1[tid * 2 + 1];
    float4 y0 = p2[tid * 2], y1 = p2[tid * 2 + 1];

    float s1 = x0.x*x0.x + x0.y*x0.y + x0.z*x0.z + x0.w*x0.w
             + x1.x*x1.x + x1.y*x1.y + x1.z*x1.z + x1.w*x1.w;
    float s2 = y0.x*y0.x + y0.y*y0.y + y0.z*y0.z + y0.w*y0.w
             + y1.x*y1.x + y1.y*y1.y + y1.z*y1.z + y1.w*y1.w;
    float dd = x0.x*y0.x + x0.y*y0.y + x0.z*y0.z + x0.w*y0.w
             + x1.x*y1.x + x1.y*y1.y + x1.z*y1.z + x1.w*y1.w;

    #pragma unroll
    for (int m = 1; m < 64; m <<= 1) {
        s1 += __shfl_xor(s1, m);
        s2 += __shfl_xor(s2, m);
        dd += __shfl_xor(dd, m);
    }
    __shared__ float red[3][4];
    if (lane == 0) { red[0][wave] = s1; red[1][wave] = s2; red[2][wave] = dd; }
    __syncthreads();
    s1 = red[0][0] + red[0][1] + red[0][2] + red[0][3];
    s2 = red[1][0] + red[1][1] + red[1][2] + red[1][3];
    dd = red[2][0] + red[2][1] + red[2][2] + red[2][3];

    const float inv1 = rsqrtf(s1), inv2 = rsqrtf(s2);
    if (tid == 0) {
        float p = dd * inv1 * inv2 * INV_T;   // pos in full fp32 precision
        pos[row] = p;
        pos[row + N_ROWS] = p;
    }

    const float a = inv1 * SCL4, b = inv2 * SCL4;
    unsigned int pa =  f2fp4(x0.x * a)        | (f2fp4(x0.y * a) << 4)
                    | (f2fp4(x0.z * a) << 8)  | (f2fp4(x0.w * a) << 12)
                    | (f2fp4(x1.x * a) << 16) | (f2fp4(x1.y * a) << 20)
                    | (f2fp4(x1.z * a) << 24) | (f2fp4(x1.w * a) << 28);
    unsigned int pb =  f2fp4(y0.x * b)        | (f2fp4(y0.y * b) << 4)
                    | (f2fp4(y0.z * b) << 8)  | (f2fp4(y0.w * b) << 12)
                    | (f2fp4(y1.x * b) << 16) | (f2fp4(y1.y * b) << 20)
                    | (f2fp4(y1.z * b) << 24) | (f2fp4(y1.w * b) << 28);
    *(unsigned int*)(reps + (size_t)row * RBYTES + tid * 4) = pa;
    *(unsigned int*)(reps + (size_t)(N_ROWS + row) * RBYTES + tid * 4) = pb;
}

// ---------------- kernel 2: 256x128-tile S = reps@reps^T, MX-fp4 K=128 ------
// Structure: 4 waves (2 row-halves x 2 col-halves), 128x64 output per wave
// (8 A-frags x 4 B-frags = 32 MFMA per K-step -> MFMA pipe > LDS pipe).
// Triple-buffered LDS (3 x 24 KiB), prefetch 2 K-steps ahead via
// global_load_lds; per step only `s_waitcnt vmcnt(6)` (own loads for the
// CURRENT buffer) + ONE raw s_barrier -- loads for the next buffers stay in
// flight across the barrier (no vmcnt(0) drain in the main loop).
// Coverage rule: launch blocks (ri, cj) with cj >= 2*ri; per element add
// exp only when c > r, crediting both rowsum[r] (srow) and rowsum[c] (scol).
// Every (r,c), c>r lands in exactly one launched block.
__global__ __launch_bounds__(256, 2) void simclr_gemm(
    const unsigned char* __restrict__ reps, float* __restrict__ rowsum)
{
    __shared__ __align__(16) unsigned char L[3 * BUFB];   // 72 KiB

    // linear block id -> (ri, cj), cj in [2*ri, 64); base(ri) = ri*(65-ri)
    const int t = blockIdx.x;
    int ri = (int)((65.0f - sqrtf(4225.0f - 4.0f * (float)t)) * 0.5f);
    while (ri * (65 - ri) > t) --ri;
    while ((ri + 1) * (64 - ri) <= t) ++ri;
    const int cj = 2 * ri + (t - ri * (65 - ri));

    const int row0 = ri * BM;        // 256-row tile
    const int col0 = cj * BN;        // 128-col tile

    const int tid  = threadIdx.x;
    const int lane = tid & 63, wave = tid >> 6;
    const int wr = wave >> 1, wc = wave & 1;   // 2x2 waves over 256x128
    const int quad = lane >> 4, l16 = lane & 15;

    // wave whose 128x64 sub-tile is entirely below the diagonal does no MFMA
    // (acc would be fully masked); it still stages + hits every barrier.
    const bool deadW = (cj == 2 * ri) && (wr == 1);

    // staging: 1536 chunks of 16 B per buffer (A: 1024, B: 512), linear LDS.
    // wave w covers chunks [w*384, w*384+384) as 6 calls of 64 lanes.
    const unsigned char* gsrc[6];
    int lofs[6];
    #pragma unroll
    for (int c = 0; c < 6; ++c) {
        const int m   = wave * 384 + c * 64 + lane;   // chunk id in buffer
        const int opB = (m >= ABYTES / 16);           // >= 1024 -> B operand
        const int mm  = opB ? m - ABYTES / 16 : m;
        const int gr  = (opB ? col0 : row0) + (mm >> 2);
        gsrc[c] = reps + (size_t)gr * RBYTES + (mm & 3) * 16;
        lofs[c] = m * 16;
    }

    floatx4 acc[8][4];
    #pragma unroll
    for (int i = 0; i < 8; ++i)
        #pragma unroll
        for (int j = 0; j < 4; ++j)
            acc[i][j] = floatx4{0.f, 0.f, 0.f, 0.f};

    // prologue: steps 0,1 -> buffers 0,1 (6 loads each, in flight = 12)
    #pragma unroll
    for (int c = 0; c < 6; ++c) GLOAD16(gsrc[c],        &L[lofs[c]]);
    #pragma unroll
    for (int c = 0; c < 6; ++c) GLOAD16(gsrc[c] + KBYT, &L[BUFB + lofs[c]]);

    int cur = 0;
    #pragma unroll 1
    for (int i = 0; i < NITER; ++i) {
        // own 6 loads for buffer `cur` are the oldest outstanding; leave the
        // newer 6 (next buffer) in flight. Never drain to 0 mid-loop.
        if (i + 1 < NITER) asm volatile("s_waitcnt vmcnt(6)" ::: "memory");
        else               asm volatile("s_waitcnt vmcnt(0)" ::: "memory");
        __builtin_amdgcn_s_barrier();        // all waves' loads now visible;
        asm volatile("" ::: "memory");       // pin GLOADs below the barrier

        if (i + 2 < NITER) {                 // prefetch step i+2
            int pf = cur + 2; if (pf >= 3) pf -= 3;
            unsigned char* Lp = &L[pf * BUFB];
            const int ko = (i + 2) * KBYT;
            #pragma unroll
            for (int c = 0; c < 6; ++c) GLOAD16(gsrc[c] + ko, Lp + lofs[c]);
        }

        if (!deadW) {
            const unsigned char* Lc = &L[cur * BUFB];
            // B frags: 4 x 16 B (32 fp4 elems, k-chunk = quad)
            intx8 b8[4];
            #pragma unroll
            for (int j = 0; j < 4; ++j) {
                intx4 bv = *(const intx4*)(Lc + ABYTES
                             + (wc * 64 + j * 16 + l16) * KBYT + quad * 16);
                b8[j] = intx8{bv[0], bv[1], bv[2], bv[3], 0, 0, 0, 0};
            }
            #pragma unroll
            for (int fi = 0; fi < 8; ++fi) {
                intx4 av = *(const intx4*)(Lc
                             + (wr * 128 + fi * 16 + l16) * KBYT + quad * 16);
                intx8 a8 = intx8{av[0], av[1], av[2], av[3], 0, 0, 0, 0};
                __builtin_amdgcn_s_setprio(1);
                #pragma unroll
                for (int j = 0; j < 4; ++j)
                    acc[fi][j] = __builtin_amdgcn_mfma_scale_f32_16x16x128_f8f6f4(
                        a8, b8[j], acc[fi][j],
                        4, 4,                      // cbsz=fp4(A), blgp=fp4(B)
                        0, 0x7F7F7F7Fu,            // scale_a = 1.0 (E8M0)
                        0, 0x7F7F7F7Fu);           // scale_b = 1.0
                __builtin_amdgcn_s_setprio(0);
            }
        }
        cur = (cur == 2) ? 0 : cur + 1;
    }

    // Epilogue: C/D layout col = l16, row = quad*4 + reg.
    // Count only c > r; credit srow (this row) AND scol (mirror row).
    const float descale = INV_T / (SCL4 * SCL4);   // 1/2048
    if (!deadW) {
        float scol[4] = {0.f, 0.f, 0.f, 0.f};
        #pragma unroll
        for (int fi = 0; fi < 8; ++fi) {
            const int rbase = row0 + wr * 128 + fi * 16 + quad * 4;
            float srow[4] = {0.f, 0.f, 0.f, 0.f};
            #pragma unroll
            for (int j = 0; j < 4; ++j) {
                const int c = col0 + wc * 64 + j * 16 + l16;
                #pragma unroll
                for (int rr = 0; rr < 4; ++rr) {
                    float e = (c > rbase + rr)
                            ? __expf(acc[fi][j][rr] * descale) : 0.f;
                    srow[rr] += e;
                    scol[j]  += e;
                }
            }
            #pragma unroll
            for (int rr = 0; rr < 4; ++rr) {
                #pragma unroll
                for (int m = 1; m < 16; m <<= 1)
                    srow[rr] += __shfl_xor(srow[rr], m);
            }
            if (l16 == 0) {
                #pragma unroll
                for (int rr = 0; rr < 4; ++rr)
                    atomicAdd(&rowsum[rbase + rr], srow[rr]);
            }
        }
        #pragma unroll
        for (int j = 0; j < 4; ++j) {
            scol[j] += __shfl_xor(scol[j], 16);
            scol[j] += __shfl_xor(scol[j], 32);
        }
        if (quad == 0) {
            #pragma unroll
            for (int j = 0; j < 4; ++j)
                atomicAdd(&rowsum[col0 + wc * 64 + j * 16 + l16], scol[j]);
        }
    }
}

// ---------------- kernel 3: mean(log(rowsum) - pos) ----------------
__global__ __launch_bounds__(1024) void finalize_kernel(
    const float* __restrict__ rowsum, const float* __restrict__ pos,
    float* __restrict__ out)
{
    const int tid = threadIdx.x;
    const int lane = tid & 63, wave = tid >> 6;
    float s = 0.f;
    for (int r = tid; r < TOT; r += 1024) s += logf(rowsum[r]) - pos[r];
    #pragma unroll
    for (int m = 1; m < 64; m <<= 1) s += __shfl_xor(s, m);
    __shared__ float red[16];
    if (lane == 0) red[wave] = s;
    __syncthreads();
    if (tid == 0) {
        float t = 0.f;
        #pragma unroll
        for (int w = 0; w < 16; ++w) t += red[w];
        out[0] = t * (1.0f / TOT);
    }
}

extern "C" void kernel_launch(void* const* d_in, const int* in_sizes, int n_in,
                              void* d_out, int out_size, void* d_ws, size_t ws_size,
                              hipStream_t stream)
{
    const float* z1 = (const float*)d_in[0];
    const float* z2 = (const float*)d_in[1];
    float* out = (float*)d_out;

    char* w = (char*)d_ws;
    unsigned char* reps = (unsigned char*)w;                 // 8 MiB fp4 [8192][1024B]
    float* pos    = (float*)(w + (size_t)TOT * RBYTES);      // 32 KiB
    float* rowsum = pos + TOT;                               // 32 KiB

    normalize_kernel<<<N_ROWS, 256, 0, stream>>>(z1, z2, reps, pos, rowsum);
    simclr_gemm<<<NBLK, 256, 0, stream>>>(reps, rowsum);
    finalize_kernel<<<1, 1024, 0, stream>>>(rowsum, pos, out);
}